// Round 22
// baseline (59.191 us; speedup 1.0000x reference)
//
#include <hip/hip_runtime.h>
#include <hip/hip_bf16.h>

#define NTOK 1024
#define EMB  1024
#define NH   16
#define HD   64
#define NS   128

typedef unsigned short u16;
typedef unsigned int uint;
typedef __attribute__((ext_vector_type(8))) unsigned short ushort8v;
typedef __attribute__((ext_vector_type(8))) _Float16 half8v;
typedef __attribute__((ext_vector_type(4))) float f32x4;

__device__ __forceinline__ u16 f2h_bits(float f) {
  union { _Float16 h; u16 u; } x; x.h = (_Float16)f; return x.u;
}

__device__ __forceinline__ void gload16(const u16* g, u16* l) {
  __builtin_amdgcn_global_load_lds(
      (const __attribute__((address_space(1))) uint*)g,
      (__attribute__((address_space(3))) uint*)l, 16, 0, 0);
}

// ---------------------------------------------------------------------------
// cvt_mask: z 0-2 = query/key/value fp32->f16, z 3-6 = Wq/Wk/Wv/Wo fp32->f16,
// z 7 = sampled-set bitmask build (frozen from R11).
// ---------------------------------------------------------------------------
__global__ __launch_bounds__(256) void cvt_mask(const float* __restrict__ S0,
                                                const float* __restrict__ S1,
                                                const float* __restrict__ S2,
                                                const float* __restrict__ S3,
                                                const float* __restrict__ S4,
                                                const float* __restrict__ S5,
                                                const float* __restrict__ S6,
                                                const int* __restrict__ samples,
                                                u16* __restrict__ D,
                                                uint* __restrict__ maskg) {
  const int z = blockIdx.y;
  const int t = threadIdx.x;
  if (z == 7) {
    __shared__ uint m[32];
    const int i = blockIdx.x;
    if (t < 32) m[t] = 0u;
    __syncthreads();
    if (t < NS) {
      const int c = samples[(size_t)i * NS + t];
      atomicOr(&m[c >> 5], 1u << (c & 31));
    }
    __syncthreads();
    if (t < 32) maskg[(size_t)i * 32 + t] = m[t];
    return;
  }
  const float* S;
  switch (z) {
    case 0: S = S0; break;
    case 1: S = S1; break;
    case 2: S = S2; break;
    case 3: S = S3; break;
    case 4: S = S4; break;
    case 5: S = S5; break;
    default: S = S6; break;
  }
  const int idx = blockIdx.x * 256 + t;
  const float4 f = ((const float4*)S)[idx];
  ushort4 p;
  p.x = f2h_bits(f.x); p.y = f2h_bits(f.y);
  p.z = f2h_bits(f.z); p.w = f2h_bits(f.w);
  ((ushort4*)(D + ((size_t)z << 20)))[idx] = p;
}

// ---------------------------------------------------------------------------
// gemm5: counted-vmcnt double-buffered f16 GEMM, 64x64 tile, BK=64
// (frozen from R21). Used for the output projection (256 blocks, exact fit).
// ---------------------------------------------------------------------------
template<bool OUT_F16>
__global__ __launch_bounds__(256) void gemm5(const u16* __restrict__ Ab,
                                             const u16* __restrict__ Bb,
                                             const float* __restrict__ b0,
                                             const float* __restrict__ b1,
                                             const float* __restrict__ b2,
                                             void* __restrict__ Cp) {
  __shared__ u16 As[2][64 * 64];
  __shared__ u16 Bs[2][64 * 64];

  const int t = threadIdx.x;
  const int lane = t & 63;
  const int w = t >> 6;
  const int wr = w >> 1, wc = w & 1;
  const int m0 = blockIdx.y * 64;
  const int n0 = blockIdx.x * 64;
  const int z = blockIdx.z;

  const u16* Az = Ab + ((size_t)z << 20);
  const u16* Bz = Bb + ((size_t)z << 20);
  const float* bsel = (z == 0) ? b0 : ((z == 1) ? b1 : b2);

  const int sR  = lane >> 3;
  const int chO = ((lane & 7) ^ sR) * 8;
  const int row0 = w * 16 + sR;
  const int row1 = row0 + 8;
  const u16* gA0 = Az + (size_t)(m0 + row0) * 1024 + chO;
  const u16* gA1 = Az + (size_t)(m0 + row1) * 1024 + chO;
  const u16* gB0 = Bz + (size_t)(n0 + row0) * 1024 + chO;
  const u16* gB1 = Bz + (size_t)(n0 + row1) * 1024 + chO;

  const int fr = lane & 15;
  const int fq = lane >> 4;
  int offA[2][2], offB[2][2];
#pragma unroll
  for (int m = 0; m < 2; m++) {
    const int R = wr * 32 + m * 16 + fr;
#pragma unroll
    for (int kk = 0; kk < 2; kk++)
      offA[m][kk] = R * 64 + (((kk * 4 + fq) ^ (R & 7)) * 8);
  }
#pragma unroll
  for (int n = 0; n < 2; n++) {
    const int R = wc * 32 + n * 16 + fr;
#pragma unroll
    for (int kk = 0; kk < 2; kk++)
      offB[n][kk] = R * 64 + (((kk * 4 + fq) ^ (R & 7)) * 8);
  }

  f32x4 acc[2][2];
#pragma unroll
  for (int m = 0; m < 2; m++)
#pragma unroll
    for (int n = 0; n < 2; n++) acc[m][n] = (f32x4){0.f, 0.f, 0.f, 0.f};

  gload16(gA0, &As[0][(size_t)(w * 16) * 64]);
  gload16(gA1, &As[0][(size_t)(w * 16 + 8) * 64]);
  gload16(gB0, &Bs[0][(size_t)(w * 16) * 64]);
  gload16(gB1, &Bs[0][(size_t)(w * 16 + 8) * 64]);

  for (int kt = 0; kt < 16; kt++) {
    const int db = kt & 1;
    if (kt < 15) {
      const int k1 = (kt + 1) * 64;
      gload16(gA0 + k1, &As[db ^ 1][(size_t)(w * 16) * 64]);
      gload16(gA1 + k1, &As[db ^ 1][(size_t)(w * 16 + 8) * 64]);
      gload16(gB0 + k1, &Bs[db ^ 1][(size_t)(w * 16) * 64]);
      gload16(gB1 + k1, &Bs[db ^ 1][(size_t)(w * 16 + 8) * 64]);
      asm volatile("s_waitcnt vmcnt(4)" ::: "memory");
    } else {
      asm volatile("s_waitcnt vmcnt(0)" ::: "memory");
    }
    __builtin_amdgcn_s_barrier();
    __builtin_amdgcn_sched_barrier(0);

#pragma unroll
    for (int kk = 0; kk < 2; kk++) {
      half8v a0 = *(const half8v*)&As[db][offA[0][kk]];
      half8v a1 = *(const half8v*)&As[db][offA[1][kk]];
      half8v bv0 = *(const half8v*)&Bs[db][offB[0][kk]];
      half8v bv1 = *(const half8v*)&Bs[db][offB[1][kk]];
      acc[0][0] = __builtin_amdgcn_mfma_f32_16x16x32_f16(a0, bv0, acc[0][0], 0, 0, 0);
      acc[0][1] = __builtin_amdgcn_mfma_f32_16x16x32_f16(a0, bv1, acc[0][1], 0, 0, 0);
      acc[1][0] = __builtin_amdgcn_mfma_f32_16x16x32_f16(a1, bv0, acc[1][0], 0, 0, 0);
      acc[1][1] = __builtin_amdgcn_mfma_f32_16x16x32_f16(a1, bv1, acc[1][1], 0, 0, 0);
    }

    asm volatile("s_waitcnt lgkmcnt(0)" ::: "memory");
    __builtin_amdgcn_s_barrier();
    __builtin_amdgcn_sched_barrier(0);
  }

  u16*   Cb = (u16*)Cp   + ((size_t)z << 20);
  float* Cf = (float*)Cp + ((size_t)z << 20);

  if (OUT_F16 && z == 2) {
#pragma unroll
    for (int n = 0; n < 2; n++) {
      const int col = n0 + wc * 32 + n * 16 + fr;
      const float bn = bsel[col];
#pragma unroll
      for (int m = 0; m < 2; m++) {
        const int rbase = m0 + wr * 32 + m * 16 + fq * 4;
        ushort4 pk;
        pk.x = f2h_bits(acc[m][n][0] + bn);
        pk.y = f2h_bits(acc[m][n][1] + bn);
        pk.z = f2h_bits(acc[m][n][2] + bn);
        pk.w = f2h_bits(acc[m][n][3] + bn);
        *(ushort4*)&Cb[(size_t)col * 1024 + rbase] = pk;
      }
    }
    return;
  }

#pragma unroll
  for (int n = 0; n < 2; n++) {
    const int col = n0 + wc * 32 + n * 16 + fr;
    const float bn = bsel[col];
#pragma unroll
    for (int m = 0; m < 2; m++) {
      const int rbase = m0 + wr * 32 + m * 16 + fq * 4;
#pragma unroll
      for (int r = 0; r < 4; r++) {
        const float val = acc[m][n][r] + bn;
        if constexpr (OUT_F16)
          Cb[(size_t)(rbase + r) * 1024 + col] = f2h_bits(val);
        else
          Cf[(size_t)(rbase + r) * 1024 + col] = val;
      }
    }
  }
}

// ---------------------------------------------------------------------------
// gemm6: QKV GEMM, 128x128 tile, BK=64, 4 waves (wave = 64x64, acc[4][4]).
// 0.5 ds_read per MFMA (vs gemm5's 1.0) and half the staging-write bytes per
// FLOP -> per-CU LDS cycles drop ~2x; grid 8x8x3 = 192 blocks (0.75/CU is
// the cost, LDS efficiency pays for it). Same counted-vmcnt discipline
// (8 gloads/thread/step, vmcnt(8)); same (row&7) XOR involution.
// z==2 stores C transposed (Vt[d][token]).
// ---------------------------------------------------------------------------
__global__ __launch_bounds__(256) void gemm6(const u16* __restrict__ Ab,
                                             const u16* __restrict__ Bb,
                                             const float* __restrict__ b0,
                                             const float* __restrict__ b1,
                                             const float* __restrict__ b2,
                                             u16* __restrict__ Cp) {
  __shared__ u16 As[2][128 * 64];   // 16 KB per buffer
  __shared__ u16 Bs[2][128 * 64];

  const int t = threadIdx.x;
  const int lane = t & 63;
  const int w = t >> 6;
  const int wr = w >> 1, wc = w & 1;
  const int m0 = blockIdx.y * 128;
  const int n0 = blockIdx.x * 128;
  const int z = blockIdx.z;

  const u16* Az = Ab + ((size_t)z << 20);
  const u16* Bz = Bb + ((size_t)z << 20);
  const float* bsel = (z == 0) ? b0 : ((z == 1) ? b1 : b2);

  // ---- staging: wave w stages rows w*32 + {0,8,16,24} + sR (4 gloads/op) ----
  const int sR  = lane >> 3;                  // 0..7; row&7 == sR
  const int chO = ((lane & 7) ^ sR) * 8;      // pre-swizzled source chunk
  const u16* gA = Az + (size_t)(m0 + w * 32 + sR) * 1024 + chO;
  const u16* gB = Bz + (size_t)(n0 + w * 32 + sR) * 1024 + chO;

  // ---- fragment read offsets ----
  const int fr = lane & 15;
  const int fq = lane >> 4;
  int offA[4][2], offB[4][2];
#pragma unroll
  for (int m = 0; m < 4; m++) {
    const int R = wr * 64 + m * 16 + fr;
#pragma unroll
    for (int kk = 0; kk < 2; kk++)
      offA[m][kk] = R * 64 + (((kk * 4 + fq) ^ (R & 7)) * 8);
  }
#pragma unroll
  for (int n = 0; n < 4; n++) {
    const int R = wc * 64 + n * 16 + fr;
#pragma unroll
    for (int kk = 0; kk < 2; kk++)
      offB[n][kk] = R * 64 + (((kk * 4 + fq) ^ (R & 7)) * 8);
  }

  f32x4 acc[4][4];
#pragma unroll
  for (int m = 0; m < 4; m++)
#pragma unroll
    for (int n = 0; n < 4; n++) acc[m][n] = (f32x4){0.f, 0.f, 0.f, 0.f};

  auto STAGE = [&](int k0, int b_) {
#pragma unroll
    for (int j = 0; j < 4; j++) {
      gload16(gA + (size_t)(j * 8) * 1024 + k0,
              &As[b_][(size_t)(w * 32 + j * 8) * 64]);
      gload16(gB + (size_t)(j * 8) * 1024 + k0,
              &Bs[b_][(size_t)(w * 32 + j * 8) * 64]);
    }
  };

  STAGE(0, 0);

  for (int kt = 0; kt < 16; kt++) {
    const int db = kt & 1;
    if (kt < 15) {
      STAGE((kt + 1) * 64, db ^ 1);
      asm volatile("s_waitcnt vmcnt(8)" ::: "memory");  // kt landed; kt+1 in flight
    } else {
      asm volatile("s_waitcnt vmcnt(0)" ::: "memory");
    }
    __builtin_amdgcn_s_barrier();
    __builtin_amdgcn_sched_barrier(0);

#pragma unroll
    for (int kk = 0; kk < 2; kk++) {
      half8v a[4], b[4];
#pragma unroll
      for (int m = 0; m < 4; m++) a[m] = *(const half8v*)&As[db][offA[m][kk]];
#pragma unroll
      for (int n = 0; n < 4; n++) b[n] = *(const half8v*)&Bs[db][offB[n][kk]];
#pragma unroll
      for (int m = 0; m < 4; m++)
#pragma unroll
        for (int n = 0; n < 4; n++)
          acc[m][n] = __builtin_amdgcn_mfma_f32_16x16x32_f16(a[m], b[n], acc[m][n], 0, 0, 0);
    }

    asm volatile("s_waitcnt lgkmcnt(0)" ::: "memory");
    __builtin_amdgcn_s_barrier();
    __builtin_amdgcn_sched_barrier(0);
  }

  u16* Cb = Cp + ((size_t)z << 20);

  if (z == 2) {
    // transposed store: Vt[col][row]
#pragma unroll
    for (int n = 0; n < 4; n++) {
      const int col = n0 + wc * 64 + n * 16 + fr;
      const float bn = bsel[col];
#pragma unroll
      for (int m = 0; m < 4; m++) {
        const int rbase = m0 + wr * 64 + m * 16 + fq * 4;
        ushort4 pk;
        pk.x = f2h_bits(acc[m][n][0] + bn);
        pk.y = f2h_bits(acc[m][n][1] + bn);
        pk.z = f2h_bits(acc[m][n][2] + bn);
        pk.w = f2h_bits(acc[m][n][3] + bn);
        *(ushort4*)&Cb[(size_t)col * 1024 + rbase] = pk;
      }
    }
    return;
  }

#pragma unroll
  for (int n = 0; n < 4; n++) {
    const int col = n0 + wc * 64 + n * 16 + fr;
    const float bn = bsel[col];
#pragma unroll
    for (int m = 0; m < 4; m++) {
      const int rbase = m0 + wr * 64 + m * 16 + fq * 4;
#pragma unroll
      for (int r = 0; r < 4; r++)
        Cb[(size_t)(rbase + r) * 1024 + col] = f2h_bits(acc[m][n][r] + bn);
    }
  }
}

// ---------------------------------------------------------------------------
// attn15 (frozen from R20): 8-wave blocks (2 waves/SIMD), double-buffered
// K/V with counted vmcnt, swapped-operand scoring, packed Ps writes.
// ---------------------------------------------------------------------------
__global__ __launch_bounds__(512) void attn15(const u16* __restrict__ Qh,
                                              const u16* __restrict__ Kh,
                                              const u16* __restrict__ Vtg,
                                              const uint* __restrict__ maskg,
                                              u16* __restrict__ O) {
  const int h  = blockIdx.x;
  const int qt = blockIdx.y;
  const int t  = threadIdx.x;
  const int wid = t >> 6;          // 0..7
  const int qg  = wid >> 1;        // q-row group 0..3
  const int kh  = wid & 1;         // key half 0..1
  const int lane = t & 63;
  const int fr = lane & 15, fq = lane >> 4;

  __shared__ u16 Kl[2][128 * 64];
  __shared__ u16 Vl[2][64 * 128];
  __shared__ u16 Ps[8][16][72];
  __shared__ uint Ms[64][36];
  __shared__ float Obuf[4][16][64];
  __shared__ float Lb2[8][16];

  {
    const uint4* src = (const uint4*)(maskg + (size_t)qt * 64 * 32);
    *(uint4*)&Ms[t >> 3][(t & 7) * 4] = src[t];
  }

  half8v qa0, qa1;
  {
    const u16* qp = Qh + (size_t)(qt * 64 + qg * 16 + fr) * EMB + h * HD + fq * 8;
    qa0 = *(const half8v*)qp;
    qa1 = *(const half8v*)(qp + 32);
  }

  const int kR3 = lane >> 3;
  const int kChO = ((lane & 7) ^ (kR3 & 7)) * 8;
  const u16* kBase = Kh + h * HD + kChO;
  const int vSub = lane >> 4;
  const int vCh  = lane & 15;
  const u16* vBase = Vtg + (size_t)h * HD * NTOK;

  auto STAGE = [&](int kt_, int b_) {
#pragma unroll
    for (int ii = 0; ii < 2; ii++) {
      const int row = wid * 16 + ii * 8 + kR3;
      gload16(kBase + (size_t)(kt_ * 128 + row) * EMB,
              &Kl[b_][(wid * 16 + ii * 8) * 64]);
    }
#pragma unroll
    for (int ii = 0; ii < 2; ii++) {
      const int d = wid * 8 + ii * 4 + vSub;
      const int ch = (vCh ^ (d & 15)) * 8;
      gload16(vBase + (size_t)d * NTOK + kt_ * 128 + ch,
              &Vl[b_][(wid * 8 + ii * 4) * 128]);
    }
  };

  f32x4 oacc[4];
#pragma unroll
  for (int ds = 0; ds < 4; ds++) oacc[ds] = (f32x4){0.f, 0.f, 0.f, 0.f};
  float lsum = 0.f;

  STAGE(0, 0);

  for (int kt = 0; kt < 8; kt++) {
    if (kt < 7) {
      STAGE(kt + 1, (kt + 1) & 1);
      asm volatile("s_waitcnt vmcnt(4)" ::: "memory");
    } else {
      asm volatile("s_waitcnt vmcnt(0)" ::: "memory");
    }
    asm volatile("s_waitcnt lgkmcnt(0)" ::: "memory");
    __builtin_amdgcn_s_barrier();
    __builtin_amdgcn_sched_barrier(0);

    const u16* Kc = &Kl[kt & 1][0];
    const u16* Vc = &Vl[kt & 1][0];

    const uint2 mq = *(const uint2*)&Ms[qg * 16 + fr][kt * 4 + kh * 2];

#pragma unroll
    for (int jb = 0; jb < 4; jb++) {
      f32x4 s = (f32x4){0.f, 0.f, 0.f, 0.f};
      const int R = kh * 64 + jb * 16 + fr;
      const half8v b0 = *(const half8v*)&Kc[R * 64 + (fq ^ (fr & 7)) * 8];
      const half8v b1 = *(const half8v*)&Kc[R * 64 + ((4 + fq) ^ (fr & 7)) * 8];
      s = __builtin_amdgcn_mfma_f32_16x16x32_f16(b0, qa0, s, 0, 0, 0);
      s = __builtin_amdgcn_mfma_f32_16x16x32_f16(b1, qa1, s, 0, 0, 0);
      const uint mw = (jb >> 1) ? mq.y : mq.x;
      const int bb = (jb & 1) * 16 + fq * 4;
      ushort4 pk;
#pragma unroll
      for (int r = 0; r < 4; r++) {
        const float p = ((mw >> (bb + r)) & 1u) ? __expf(s[r] * 0.03125f) : 0.f;
        lsum += p;
        ((u16*)&pk)[r] = f2h_bits(p);
      }
      *(ushort4*)&Ps[wid][fr][jb * 16 + fq * 4] = pk;
    }
    asm volatile("s_waitcnt lgkmcnt(0)" ::: "memory");
    __builtin_amdgcn_sched_barrier(0);

    __builtin_amdgcn_s_setprio(1);
#pragma unroll
    for (int jc = 0; jc < 2; jc++) {
      const half8v pa = *(const half8v*)&Ps[wid][fr][jc * 32 + fq * 8];
#pragma unroll
      for (int ds = 0; ds < 4; ds++) {
        const int d = ds * 16 + fr;
        const half8v vb =
            *(const half8v*)&Vc[d * 128 + ((kh * 8 + jc * 4 + fq) ^ fr) * 8];
        oacc[ds] = __builtin_amdgcn_mfma_f32_16x16x32_f16(pa, vb, oacc[ds], 0, 0, 0);
      }
    }
    __builtin_amdgcn_s_setprio(0);
    __builtin_amdgcn_s_barrier();
  }

  lsum += __shfl_xor(lsum, 16, 64);
  lsum += __shfl_xor(lsum, 32, 64);
  if (fq == 0) Lb2[wid][fr] = lsum;

  if (kh == 1) {
#pragma unroll
    for (int ds = 0; ds < 4; ds++)
#pragma unroll
      for (int r = 0; r < 4; r++)
        Obuf[qg][fq * 4 + r][ds * 16 + fr] = oacc[ds][r];
  }
  __syncthreads();
  if (kh == 0) {
    float ls[4];
#pragma unroll
    for (int r = 0; r < 4; r++)
      ls[r] = Lb2[qg * 2][fq * 4 + r] + Lb2[qg * 2 + 1][fq * 4 + r];
#pragma unroll
    for (int ds = 0; ds < 4; ds++) {
#pragma unroll
      for (int r = 0; r < 4; r++) {
        const float v = oacc[ds][r] + Obuf[qg][fq * 4 + r][ds * 16 + fr];
        O[(size_t)(qt * 64 + qg * 16 + fq * 4 + r) * EMB + h * HD + ds * 16 + fr] =
            f2h_bits(v / ls[r]);
      }
    }
  }
}

extern "C" void kernel_launch(void* const* d_in, const int* in_sizes, int n_in,
                              void* d_out, int out_size, void* d_ws, size_t ws_size,
                              hipStream_t stream) {
  const float* query = (const float*)d_in[0];
  const float* key   = (const float*)d_in[1];
  const float* value = (const float*)d_in[2];
  const float* Wq    = (const float*)d_in[3];
  const float* bq    = (const float*)d_in[4];
  const float* Wk    = (const float*)d_in[5];
  const float* bk    = (const float*)d_in[6];
  const float* Wv    = (const float*)d_in[7];
  const float* bv    = (const float*)d_in[8];
  const float* Wo    = (const float*)d_in[9];
  const float* bo    = (const float*)d_in[10];
  const int* samples = (const int*)d_in[11];
  float* out = (float*)d_out;

  u16* base = (u16*)d_ws;
  u16* Xh = base;
  u16* Wh = base + ((size_t)3 << 20);
  u16* Qh = base + ((size_t)7 << 20);
  u16* Kh = base + ((size_t)8 << 20);
  u16* Vt = base + ((size_t)9 << 20);
  u16* O  = base + ((size_t)10 << 20);
  uint* maskg = (uint*)(base + ((size_t)11 << 20));

  cvt_mask<<<dim3(1024, 8), 256, 0, stream>>>(
      query, key, value, Wq, Wk, Wv, Wo, samples, Xh, maskg);

  gemm6<<<dim3(8, 8, 3), 256, 0, stream>>>(Xh, Wh, bq, bk, bv, Qh);

  attn15<<<dim3(NH, 16), 512, 0, stream>>>(Qh, Kh, Vt, maskg, O);

  gemm5<false><<<dim3(16, 16, 1), 256, 0, stream>>>(O, Wh + ((size_t)3 << 20), bo, bo, bo, out);
}

// Round 23
// 52.243 us; speedup vs baseline: 1.1330x; 1.1330x over previous
//
#include <hip/hip_runtime.h>
#include <hip/hip_bf16.h>

#define NTOK 1024
#define EMB  1024
#define NH   16
#define HD   64
#define NS   128

typedef unsigned short u16;
typedef unsigned int uint;
typedef __attribute__((ext_vector_type(8))) unsigned short ushort8v;
typedef __attribute__((ext_vector_type(8))) _Float16 half8v;
typedef __attribute__((ext_vector_type(4))) float f32x4;

__device__ __forceinline__ u16 f2h_bits(float f) {
  union { _Float16 h; u16 u; } x; x.h = (_Float16)f; return x.u;
}

__device__ __forceinline__ void gload16(const u16* g, u16* l) {
  __builtin_amdgcn_global_load_lds(
      (const __attribute__((address_space(1))) uint*)g,
      (__attribute__((address_space(3))) uint*)l, 16, 0, 0);
}

// ---------------------------------------------------------------------------
// cvt_mask: z 0-2 = query/key/value fp32->f16, z 3-6 = Wq/Wk/Wv/Wo fp32->f16,
// z 7 = sampled-set bitmask build (frozen from R11).
// ---------------------------------------------------------------------------
__global__ __launch_bounds__(256) void cvt_mask(const float* __restrict__ S0,
                                                const float* __restrict__ S1,
                                                const float* __restrict__ S2,
                                                const float* __restrict__ S3,
                                                const float* __restrict__ S4,
                                                const float* __restrict__ S5,
                                                const float* __restrict__ S6,
                                                const int* __restrict__ samples,
                                                u16* __restrict__ D,
                                                uint* __restrict__ maskg) {
  const int z = blockIdx.y;
  const int t = threadIdx.x;
  if (z == 7) {
    __shared__ uint m[32];
    const int i = blockIdx.x;
    if (t < 32) m[t] = 0u;
    __syncthreads();
    if (t < NS) {
      const int c = samples[(size_t)i * NS + t];
      atomicOr(&m[c >> 5], 1u << (c & 31));
    }
    __syncthreads();
    if (t < 32) maskg[(size_t)i * 32 + t] = m[t];
    return;
  }
  const float* S;
  switch (z) {
    case 0: S = S0; break;
    case 1: S = S1; break;
    case 2: S = S2; break;
    case 3: S = S3; break;
    case 4: S = S4; break;
    case 5: S = S5; break;
    default: S = S6; break;
  }
  const int idx = blockIdx.x * 256 + t;
  const float4 f = ((const float4*)S)[idx];
  ushort4 p;
  p.x = f2h_bits(f.x); p.y = f2h_bits(f.y);
  p.z = f2h_bits(f.z); p.w = f2h_bits(f.w);
  ((ushort4*)(D + ((size_t)z << 20)))[idx] = p;
}

// ---------------------------------------------------------------------------
// gemm5: counted-vmcnt double-buffered f16 GEMM, 64x64 tile, BK=64
// (validated R21). 16 K-steps, 8 MFMA/wave/step, vmcnt(4) in-flight prefetch.
// Swizzle: LDS[row][c] = G[row][c ^ (row&7)] both sides.
// OUT_F16 && z==2 stores C transposed (Vt[d][token]).
// ---------------------------------------------------------------------------
template<bool OUT_F16>
__global__ __launch_bounds__(256) void gemm5(const u16* __restrict__ Ab,
                                             const u16* __restrict__ Bb,
                                             const float* __restrict__ b0,
                                             const float* __restrict__ b1,
                                             const float* __restrict__ b2,
                                             void* __restrict__ Cp) {
  __shared__ u16 As[2][64 * 64];
  __shared__ u16 Bs[2][64 * 64];

  const int t = threadIdx.x;
  const int lane = t & 63;
  const int w = t >> 6;
  const int wr = w >> 1, wc = w & 1;
  const int m0 = blockIdx.y * 64;
  const int n0 = blockIdx.x * 64;
  const int z = blockIdx.z;

  const u16* Az = Ab + ((size_t)z << 20);
  const u16* Bz = Bb + ((size_t)z << 20);
  const float* bsel = (z == 0) ? b0 : ((z == 1) ? b1 : b2);

  const int sR  = lane >> 3;
  const int chO = ((lane & 7) ^ sR) * 8;
  const int row0 = w * 16 + sR;
  const int row1 = row0 + 8;
  const u16* gA0 = Az + (size_t)(m0 + row0) * 1024 + chO;
  const u16* gA1 = Az + (size_t)(m0 + row1) * 1024 + chO;
  const u16* gB0 = Bz + (size_t)(n0 + row0) * 1024 + chO;
  const u16* gB1 = Bz + (size_t)(n0 + row1) * 1024 + chO;

  const int fr = lane & 15;
  const int fq = lane >> 4;
  int offA[2][2], offB[2][2];
#pragma unroll
  for (int m = 0; m < 2; m++) {
    const int R = wr * 32 + m * 16 + fr;
#pragma unroll
    for (int kk = 0; kk < 2; kk++)
      offA[m][kk] = R * 64 + (((kk * 4 + fq) ^ (R & 7)) * 8);
  }
#pragma unroll
  for (int n = 0; n < 2; n++) {
    const int R = wc * 32 + n * 16 + fr;
#pragma unroll
    for (int kk = 0; kk < 2; kk++)
      offB[n][kk] = R * 64 + (((kk * 4 + fq) ^ (R & 7)) * 8);
  }

  f32x4 acc[2][2];
#pragma unroll
  for (int m = 0; m < 2; m++)
#pragma unroll
    for (int n = 0; n < 2; n++) acc[m][n] = (f32x4){0.f, 0.f, 0.f, 0.f};

  gload16(gA0, &As[0][(size_t)(w * 16) * 64]);
  gload16(gA1, &As[0][(size_t)(w * 16 + 8) * 64]);
  gload16(gB0, &Bs[0][(size_t)(w * 16) * 64]);
  gload16(gB1, &Bs[0][(size_t)(w * 16 + 8) * 64]);

  for (int kt = 0; kt < 16; kt++) {
    const int db = kt & 1;
    if (kt < 15) {
      const int k1 = (kt + 1) * 64;
      gload16(gA0 + k1, &As[db ^ 1][(size_t)(w * 16) * 64]);
      gload16(gA1 + k1, &As[db ^ 1][(size_t)(w * 16 + 8) * 64]);
      gload16(gB0 + k1, &Bs[db ^ 1][(size_t)(w * 16) * 64]);
      gload16(gB1 + k1, &Bs[db ^ 1][(size_t)(w * 16 + 8) * 64]);
      asm volatile("s_waitcnt vmcnt(4)" ::: "memory");
    } else {
      asm volatile("s_waitcnt vmcnt(0)" ::: "memory");
    }
    __builtin_amdgcn_s_barrier();
    __builtin_amdgcn_sched_barrier(0);

#pragma unroll
    for (int kk = 0; kk < 2; kk++) {
      half8v a0 = *(const half8v*)&As[db][offA[0][kk]];
      half8v a1 = *(const half8v*)&As[db][offA[1][kk]];
      half8v bv0 = *(const half8v*)&Bs[db][offB[0][kk]];
      half8v bv1 = *(const half8v*)&Bs[db][offB[1][kk]];
      acc[0][0] = __builtin_amdgcn_mfma_f32_16x16x32_f16(a0, bv0, acc[0][0], 0, 0, 0);
      acc[0][1] = __builtin_amdgcn_mfma_f32_16x16x32_f16(a0, bv1, acc[0][1], 0, 0, 0);
      acc[1][0] = __builtin_amdgcn_mfma_f32_16x16x32_f16(a1, bv0, acc[1][0], 0, 0, 0);
      acc[1][1] = __builtin_amdgcn_mfma_f32_16x16x32_f16(a1, bv1, acc[1][1], 0, 0, 0);
    }

    asm volatile("s_waitcnt lgkmcnt(0)" ::: "memory");
    __builtin_amdgcn_s_barrier();
    __builtin_amdgcn_sched_barrier(0);
  }

  u16*   Cb = (u16*)Cp   + ((size_t)z << 20);
  float* Cf = (float*)Cp + ((size_t)z << 20);

  if (OUT_F16 && z == 2) {
#pragma unroll
    for (int n = 0; n < 2; n++) {
      const int col = n0 + wc * 32 + n * 16 + fr;
      const float bn = bsel[col];
#pragma unroll
      for (int m = 0; m < 2; m++) {
        const int rbase = m0 + wr * 32 + m * 16 + fq * 4;
        ushort4 pk;
        pk.x = f2h_bits(acc[m][n][0] + bn);
        pk.y = f2h_bits(acc[m][n][1] + bn);
        pk.z = f2h_bits(acc[m][n][2] + bn);
        pk.w = f2h_bits(acc[m][n][3] + bn);
        *(ushort4*)&Cb[(size_t)col * 1024 + rbase] = pk;
      }
    }
    return;
  }

#pragma unroll
  for (int n = 0; n < 2; n++) {
    const int col = n0 + wc * 32 + n * 16 + fr;
    const float bn = bsel[col];
#pragma unroll
    for (int m = 0; m < 2; m++) {
      const int rbase = m0 + wr * 32 + m * 16 + fq * 4;
#pragma unroll
      for (int r = 0; r < 4; r++) {
        const float val = acc[m][n][r] + bn;
        if constexpr (OUT_F16)
          Cb[(size_t)(rbase + r) * 1024 + col] = f2h_bits(val);
        else
          Cf[(size_t)(rbase + r) * 1024 + col] = val;
      }
    }
  }
}

// ---------------------------------------------------------------------------
// attn15 (frozen from R20): 8-wave blocks (2 waves/SIMD), double-buffered
// K/V with counted vmcnt, swapped-operand scoring, packed Ps writes.
// ---------------------------------------------------------------------------
__global__ __launch_bounds__(512) void attn15(const u16* __restrict__ Qh,
                                              const u16* __restrict__ Kh,
                                              const u16* __restrict__ Vtg,
                                              const uint* __restrict__ maskg,
                                              u16* __restrict__ O) {
  const int h  = blockIdx.x;
  const int qt = blockIdx.y;
  const int t  = threadIdx.x;
  const int wid = t >> 6;          // 0..7
  const int qg  = wid >> 1;        // q-row group 0..3
  const int kh  = wid & 1;         // key half 0..1
  const int lane = t & 63;
  const int fr = lane & 15, fq = lane >> 4;

  __shared__ u16 Kl[2][128 * 64];
  __shared__ u16 Vl[2][64 * 128];
  __shared__ u16 Ps[8][16][72];
  __shared__ uint Ms[64][36];
  __shared__ float Obuf[4][16][64];
  __shared__ float Lb2[8][16];

  {
    const uint4* src = (const uint4*)(maskg + (size_t)qt * 64 * 32);
    *(uint4*)&Ms[t >> 3][(t & 7) * 4] = src[t];
  }

  half8v qa0, qa1;
  {
    const u16* qp = Qh + (size_t)(qt * 64 + qg * 16 + fr) * EMB + h * HD + fq * 8;
    qa0 = *(const half8v*)qp;
    qa1 = *(const half8v*)(qp + 32);
  }

  const int kR3 = lane >> 3;
  const int kChO = ((lane & 7) ^ (kR3 & 7)) * 8;
  const u16* kBase = Kh + h * HD + kChO;
  const int vSub = lane >> 4;
  const int vCh  = lane & 15;
  const u16* vBase = Vtg + (size_t)h * HD * NTOK;

  auto STAGE = [&](int kt_, int b_) {
#pragma unroll
    for (int ii = 0; ii < 2; ii++) {
      const int row = wid * 16 + ii * 8 + kR3;
      gload16(kBase + (size_t)(kt_ * 128 + row) * EMB,
              &Kl[b_][(wid * 16 + ii * 8) * 64]);
    }
#pragma unroll
    for (int ii = 0; ii < 2; ii++) {
      const int d = wid * 8 + ii * 4 + vSub;
      const int ch = (vCh ^ (d & 15)) * 8;
      gload16(vBase + (size_t)d * NTOK + kt_ * 128 + ch,
              &Vl[b_][(wid * 8 + ii * 4) * 128]);
    }
  };

  f32x4 oacc[4];
#pragma unroll
  for (int ds = 0; ds < 4; ds++) oacc[ds] = (f32x4){0.f, 0.f, 0.f, 0.f};
  float lsum = 0.f;

  STAGE(0, 0);

  for (int kt = 0; kt < 8; kt++) {
    if (kt < 7) {
      STAGE(kt + 1, (kt + 1) & 1);
      asm volatile("s_waitcnt vmcnt(4)" ::: "memory");
    } else {
      asm volatile("s_waitcnt vmcnt(0)" ::: "memory");
    }
    asm volatile("s_waitcnt lgkmcnt(0)" ::: "memory");
    __builtin_amdgcn_s_barrier();
    __builtin_amdgcn_sched_barrier(0);

    const u16* Kc = &Kl[kt & 1][0];
    const u16* Vc = &Vl[kt & 1][0];

    const uint2 mq = *(const uint2*)&Ms[qg * 16 + fr][kt * 4 + kh * 2];

#pragma unroll
    for (int jb = 0; jb < 4; jb++) {
      f32x4 s = (f32x4){0.f, 0.f, 0.f, 0.f};
      const int R = kh * 64 + jb * 16 + fr;
      const half8v b0 = *(const half8v*)&Kc[R * 64 + (fq ^ (fr & 7)) * 8];
      const half8v b1 = *(const half8v*)&Kc[R * 64 + ((4 + fq) ^ (fr & 7)) * 8];
      s = __builtin_amdgcn_mfma_f32_16x16x32_f16(b0, qa0, s, 0, 0, 0);
      s = __builtin_amdgcn_mfma_f32_16x16x32_f16(b1, qa1, s, 0, 0, 0);
      const uint mw = (jb >> 1) ? mq.y : mq.x;
      const int bb = (jb & 1) * 16 + fq * 4;
      ushort4 pk;
#pragma unroll
      for (int r = 0; r < 4; r++) {
        const float p = ((mw >> (bb + r)) & 1u) ? __expf(s[r] * 0.03125f) : 0.f;
        lsum += p;
        ((u16*)&pk)[r] = f2h_bits(p);
      }
      *(ushort4*)&Ps[wid][fr][jb * 16 + fq * 4] = pk;
    }
    asm volatile("s_waitcnt lgkmcnt(0)" ::: "memory");
    __builtin_amdgcn_sched_barrier(0);

    __builtin_amdgcn_s_setprio(1);
#pragma unroll
    for (int jc = 0; jc < 2; jc++) {
      const half8v pa = *(const half8v*)&Ps[wid][fr][jc * 32 + fq * 8];
#pragma unroll
      for (int ds = 0; ds < 4; ds++) {
        const int d = ds * 16 + fr;
        const half8v vb =
            *(const half8v*)&Vc[d * 128 + ((kh * 8 + jc * 4 + fq) ^ fr) * 8];
        oacc[ds] = __builtin_amdgcn_mfma_f32_16x16x32_f16(pa, vb, oacc[ds], 0, 0, 0);
      }
    }
    __builtin_amdgcn_s_setprio(0);
    __builtin_amdgcn_s_barrier();
  }

  lsum += __shfl_xor(lsum, 16, 64);
  lsum += __shfl_xor(lsum, 32, 64);
  if (fq == 0) Lb2[wid][fr] = lsum;

  if (kh == 1) {
#pragma unroll
    for (int ds = 0; ds < 4; ds++)
#pragma unroll
      for (int r = 0; r < 4; r++)
        Obuf[qg][fq * 4 + r][ds * 16 + fr] = oacc[ds][r];
  }
  __syncthreads();
  if (kh == 0) {
    float ls[4];
#pragma unroll
    for (int r = 0; r < 4; r++)
      ls[r] = Lb2[qg * 2][fq * 4 + r] + Lb2[qg * 2 + 1][fq * 4 + r];
#pragma unroll
    for (int ds = 0; ds < 4; ds++) {
#pragma unroll
      for (int r = 0; r < 4; r++) {
        const float v = oacc[ds][r] + Obuf[qg][fq * 4 + r][ds * 16 + fr];
        O[(size_t)(qt * 64 + qg * 16 + fq * 4 + r) * EMB + h * HD + ds * 16 + fr] =
            f2h_bits(v / ls[r]);
      }
    }
  }
}

extern "C" void kernel_launch(void* const* d_in, const int* in_sizes, int n_in,
                              void* d_out, int out_size, void* d_ws, size_t ws_size,
                              hipStream_t stream) {
  const float* query = (const float*)d_in[0];
  const float* key   = (const float*)d_in[1];
  const float* value = (const float*)d_in[2];
  const float* Wq    = (const float*)d_in[3];
  const float* bq    = (const float*)d_in[4];
  const float* Wk    = (const float*)d_in[5];
  const float* bk    = (const float*)d_in[6];
  const float* Wv    = (const float*)d_in[7];
  const float* bv    = (const float*)d_in[8];
  const float* Wo    = (const float*)d_in[9];
  const float* bo    = (const float*)d_in[10];
  const int* samples = (const int*)d_in[11];
  float* out = (float*)d_out;

  u16* base = (u16*)d_ws;
  u16* Xh = base;
  u16* Wh = base + ((size_t)3 << 20);
  u16* Qh = base + ((size_t)7 << 20);
  u16* Kh = base + ((size_t)8 << 20);
  u16* Vt = base + ((size_t)9 << 20);
  u16* O  = base + ((size_t)10 << 20);
  uint* maskg = (uint*)(base + ((size_t)11 << 20));

  cvt_mask<<<dim3(1024, 8), 256, 0, stream>>>(
      query, key, value, Wq, Wk, Wv, Wo, samples, Xh, maskg);

  gemm5<true><<<dim3(16, 16, 3), 256, 0, stream>>>(Xh, Wh, bq, bk, bv, Qh);

  attn15<<<dim3(NH, 16), 512, 0, stream>>>(Qh, Kh, Vt, maskg, O);

  gemm5<false><<<dim3(16, 16, 1), 256, 0, stream>>>(O, Wh + ((size_t)3 << 20), bo, bo, bo, out);
}